// Round 4
// baseline (157.439 us; speedup 1.0000x reference)
//
#include <hip/hip_runtime.h>

namespace {

typedef __attribute__((ext_vector_type(2))) float f32x2;
typedef __attribute__((ext_vector_type(4))) float f32x4;

constexpr int Hd = 512, Wd = 512;
constexpr int TH = 32;             // output rows per block. TH=16 (round 2) raised
                                   // occupancy 51->60% but regressed: fill overhead
                                   // (+18% work) outweighed it. Keep 32.
constexpr int R  = 4;              // rows per LDS phase (barrier period)
constexpr int NCH = TH / R;        // 8 chunks
constexpr int RAD = 5, WS = 11;
// Transposed staging layout (round-3, kept): staged element e (column e-5) at
// slot s(e) = (e&3)*SPAN + (e>>2). Reads: one base (lane stride 16B, dense
// 1024B/wave) + 14 compile-time immediates -> conflict-free. Writes: 4 dense
// 256B segments, residual 2-way (free per m136). SQ_LDS_BANK_CONFLICT
// 8.26M -> 1.62M with zero added address VALU.
constexpr int SPAN = 131;          // ceil(522/4); row stride = 4*SPAN = 524 elems
constexpr int RSTR = 4 * SPAN;     // f32x4 elements per staged row
constexpr float C1c = 1e-4f;       // (0.01*1.0)^2
constexpr float C2c = 9e-4f;       // (0.03*1.0)^2

__device__ __forceinline__ float rcp_fast(float x) { return __builtin_amdgcn_rcpf(x); }
__device__ __forceinline__ float sgpr_f(float x) {
    return __int_as_float(__builtin_amdgcn_readfirstlane(__float_as_int(x)));
}
__device__ __forceinline__ constexpr int sw(int e) { return (e & 3) * SPAN + (e >> 2); }

// LDS 33.5 KB; VGPR target <=85 for the (512,6) tier.
__global__ __launch_bounds__(512, 6) void ssim_map_kernel(
    const float* __restrict__ img1,
    const float* __restrict__ img2,
    const float* __restrict__ kern,
    float* __restrict__ out)
{
    // packed {mS, mD, QS, QD} per column, R rows, transposed slot order
    __shared__ __align__(16) f32x4 hb[R * RSTR];   // 33.5 KB

    const int tid  = threadIdx.x;
    const int c    = tid;                       // owned column
    const int row0 = blockIdx.x * TH;
    const long pbase = (long)blockIdx.y * (long)(Hd * Wd);

    // ---- 1D gaussian (uniform -> SGPRs): g[j] = k[5][j]/sum ----
    float g[WS];
    {
        float s = 0.f;
#pragma unroll
        for (int j = 0; j < WS; ++j) s += kern[RAD * WS + j];
        const float inv = 1.0f / s;
#pragma unroll
        for (int j = 0; j < WS; ++j) g[j] = sgpr_f(kern[RAD * WS + j] * inv);
    }

    // ---- precomputed transposed write slots (loop-invariant) ----
    const int wmain = sw(c + RAD);              // staged element c+5
    int whalo = -1;
    if (c >= 1 && c <= RAD) whalo = sw(RAD - c);                       // left reflect
    else if (c >= Wd - 1 - RAD && c <= Wd - 2) whalo = sw(RAD + 1022 - c); // right

    // ---- ring accumulators, slot(out_row o) = o % 11 ----
    f32x2 aM[WS];   // {conv(S), conv(D)}
    f32x2 aQ[WS];   // {conv(S^2), conv(D^2)}
#pragma unroll
    for (int i = 0; i < WS; ++i) {
        aM[i].x = 0.f; aM[i].y = 0.f;
        aQ[i].x = 0.f; aQ[i].y = 0.f;
    }

    // ---- fill: input idx j=0..9 (rows row0-5+j), taps k<=j ----
#pragma unroll
    for (int j = 0; j < 2 * RAD; ++j) {
        int gr = row0 - RAD + j;                // uniform reflect -> SALU
        gr = (gr < 0) ? -gr : gr;
        gr = (gr >= Hd) ? (2 * Hd - 2 - gr) : gr;
        const long off = pbase + (long)gr * Wd + c;
        const float a = img1[off];
        const float b = img2[off];
        f32x2 sd; sd.x = a + b; sd.y = a - b;
        const f32x2 qq = sd * sd;               // v_pk_mul_f32
#pragma unroll
        for (int k = 0; k < WS; ++k) {
            if (k <= j) {
                const int slot = (j - k) % WS;  // static after unroll
                f32x2 w2; w2.x = g[k]; w2.y = g[k];
                aM[slot] = __builtin_elementwise_fma(w2, sd, aM[slot]);
                aQ[slot] = __builtin_elementwise_fma(w2, qq, aQ[slot]);
            }
        }
    }

    // ---- T14 prefetch (round-4): next chunk's rows live in registers.
    // Previously each V phase began with 8 dependent global loads right after
    // barrier 1 -> 300-900cy exposed per chunk on the critical path. Now loads
    // issue before barrier 2 and their latency hides under barrier2 + H + barrier1.
    // Input row for (ch,i) = row0 + RAD + ch*R + i >= 5, so only upper reflect.
    float pla[R], plb[R];
#pragma unroll
    for (int i = 0; i < R; ++i) {
        int gr = row0 + RAD + i;                // chunk 0
        gr = (gr >= Hd) ? (2 * Hd - 2 - gr) : gr;
        const long off = pbase + (long)gr * Wd + c;
        pla[i] = img1[off];
        plb[i] = img2[off];
    }

    const int hr = tid >> 7;      // horizontal: row in chunk (0..3)
    const int hu = tid & 127;     // horizontal: out cols 4hu..4hu+3

#pragma unroll
    for (int ch = 0; ch < NCH; ++ch) {
        __syncthreads();          // prev chunk's readers done before overwrite

        // ---- vertical: 1 preloaded input row -> 1 completed output row ----
#pragma unroll
        for (int i = 0; i < R; ++i) {
            const int o = ch * R + i;           // out row in band
            const int j = o + 2 * RAD;          // input idx
            const float a = pla[i];
            const float b = plb[i];
            f32x2 sd; sd.x = a + b; sd.y = a - b;
            const f32x2 qq = sd * sd;
#pragma unroll
            for (int k = 0; k < WS; ++k) {
                const int slot = (j - k) % WS;  // static after unroll
                f32x2 w2; w2.x = g[k]; w2.y = g[k];
                aM[slot] = __builtin_elementwise_fma(w2, sd, aM[slot]);
                aQ[slot] = __builtin_elementwise_fma(w2, qq, aQ[slot]);
            }
            // emit completed row o (slot o%11) -> LDS row i, transposed slot
            const int es = o % WS;
            f32x4 e;
            e.x = aM[es].x; e.y = aM[es].y;
            e.z = aQ[es].x; e.w = aQ[es].y;
            hb[i * RSTR + wmain] = e;
            if (whalo >= 0) hb[i * RSTR + whalo] = e;
            aM[es].x = 0.f; aM[es].y = 0.f;     // free slot for row o+11
            aQ[es].x = 0.f; aQ[es].y = 0.f;
        }

        // ---- issue next chunk's global loads (latency hides under H) ----
        if (ch + 1 < NCH) {
#pragma unroll
            for (int i = 0; i < R; ++i) {
                int gr = row0 + RAD + (ch + 1) * R + i;
                gr = (gr >= Hd) ? (2 * Hd - 2 - gr) : gr;
                const long off = pbase + (long)gr * Wd + c;
                pla[i] = img1[off];
                plb[i] = img2[off];
            }
        }

        __syncthreads();

        // ---- horizontal + epilogue: 4 cols x 1 row per thread ----
        f32x2 hm[4], hq[4];
#pragma unroll
        for (int j = 0; j < 4; ++j) {
            hm[j].x = 0.f; hm[j].y = 0.f;
            hq[j].x = 0.f; hq[j].y = 0.f;
        }
        // base lane-stride = 1 element (16B): dense wave reads, all offsets imm
        const f32x4* base = &hb[hr * RSTR + hu];
#pragma unroll
        for (int t = 0; t < 14; ++t) {          // staged elem 4hu+t (col 4hu+t-5)
            const f32x4 ft = base[(t & 3) * SPAN + (t >> 2)];   // ds_read_b128
            f32x2 fm; fm.x = ft.x; fm.y = ft.y;
            f32x2 fq; fq.x = ft.z; fq.y = ft.w;
#pragma unroll
            for (int j = 0; j < 4; ++j) {
                const int k = t - j;            // tap index, compile-time
                if (k >= 0 && k < WS) {
                    f32x2 w2; w2.x = g[k]; w2.y = g[k];
                    hm[j] = __builtin_elementwise_fma(w2, fm, hm[j]);
                    hq[j] = __builtin_elementwise_fma(w2, fq, hq[j]);
                }
            }
        }

        float rr[4];
#pragma unroll
        for (int j = 0; j < 4; ++j) {
            const f32x2 m = hm[j];              // {mS, mD}
            const f32x2 q = hq[j];              // {QS, QD}
            const f32x2 msq = m * m;            // {mS^2, mD^2}
            const float t1 = msq.x - msq.y;     // 4*mu1mu2
            const float t2 = msq.x + msq.y;     // 2*(mu1^2+mu2^2)
            const float q1 = q.x - q.y;         // 4*conv(ab)
            const float q2 = q.x + q.y;         // 2*conv(a^2+b^2)
            const float num = fmaf(0.5f, t1, C1c) * fmaf(0.5f, q1 - t1, C2c);
            const float den = fmaf(0.5f, t2, C1c) * fmaf(0.5f, q2 - t2, C2c);
            rr[j] = num * rcp_fast(den);
        }
        f32x4 res; res.x = rr[0]; res.y = rr[1]; res.z = rr[2]; res.w = rr[3];
        f32x4* po = (f32x4*)&out[pbase + (long)(row0 + ch * R + hr) * Wd + 4 * hu];
        *po = res;
    }
}

} // namespace

extern "C" void kernel_launch(void* const* d_in, const int* in_sizes, int n_in,
                              void* d_out, int out_size, void* d_ws, size_t ws_size,
                              hipStream_t stream) {
    const float* img1 = (const float*)d_in[0];
    const float* img2 = (const float*)d_in[1];
    const float* kern = (const float*)d_in[2];
    float* outp = (float*)d_out;
    dim3 grid(Hd / TH, 48);   // 16 bands x 48 planes = 768 blocks = 3/CU
    ssim_map_kernel<<<grid, dim3(512), 0, stream>>>(img1, img2, kern, outp);
}

// Round 6
// 144.939 us; speedup vs baseline: 1.0862x; 1.0862x over previous
//
#include <hip/hip_runtime.h>

namespace {

typedef __attribute__((ext_vector_type(2))) float f32x2;
typedef __attribute__((ext_vector_type(4))) float f32x4;

constexpr int Hd = 512, Wd = 512;
constexpr int TH = 32;             // output rows per block (round-2: TH=16 regressed)
constexpr int R  = 4;              // rows per LDS phase
constexpr int NCH = TH / R;        // 8 chunks
constexpr int RAD = 5, WS = 11;
// Transposed staging layout (round-3, kept): staged element e (column e-5) at
// slot s(e) = (e&3)*SPAN + (e>>2). Reads: one base (lane stride 16B, dense) +
// compile-time immediates, conflict-free. Writes: 4 dense 256B segments.
constexpr int SPAN = 131;
constexpr int RSTR = 4 * SPAN;     // 524 f32x4 elements per staged row
constexpr float C1c = 1e-4f;       // (0.01*1.0)^2
constexpr float C2c = 9e-4f;       // (0.03*1.0)^2

__device__ __forceinline__ float rcp_fast(float x) { return __builtin_amdgcn_rcpf(x); }
__device__ __forceinline__ float sgpr_f(float x) {
    return __int_as_float(__builtin_amdgcn_readfirstlane(__float_as_int(x)));
}
__device__ __forceinline__ constexpr int sw(int e) { return (e & 3) * SPAN + (e >> 2); }

// Round-5/6: double-buffered ping-pong, ONE barrier per chunk (16->8
// barriers/block). Period = {barrier; prefetch ch+2; H(ch) from hb[ch&1];
// V(ch+1) into hb[(ch+1)&1]}. Correctness: V(ch+1)'s writes are separated
// from H(ch-1)'s reads of the same buffer by barrier(ch); in-period H and V
// use different buffers. H ds_reads interleave with V FMAs in one scheduling
// region -> per-wave latency self-hiding instead of barrier drain.
// LDS 67 KB (2 blocks/CU).
// ROUND-5 BUG (fixed here): `es = (CH * R + i) % WS` with CH = `ch + 1`
// expanded to (ch + 1*R + i) -- unparenthesized macro arg corrupted the
// accumulator ring (absmax 852). es now derives from the parenthesized `o`.

#define VPHASE(CH, PA, PB, BUF)                                         \
    _Pragma("unroll")                                                   \
    for (int i = 0; i < R; ++i) {                                       \
        const int o = (CH) * R + i;                                     \
        const int j = o + 2 * RAD;                                      \
        const float a = (PA)[i];                                        \
        const float b = (PB)[i];                                        \
        f32x2 sd; sd.x = a + b; sd.y = a - b;                           \
        const f32x2 qq = sd * sd;                                       \
        _Pragma("unroll")                                               \
        for (int k = 0; k < WS; ++k) {                                  \
            const int slot = (j - k) % WS;   /* static after unroll */  \
            f32x2 w2; w2.x = g[k]; w2.y = g[k];                         \
            aM[slot] = __builtin_elementwise_fma(w2, sd, aM[slot]);     \
            aQ[slot] = __builtin_elementwise_fma(w2, qq, aQ[slot]);     \
        }                                                               \
        const int es = o % WS;                                          \
        f32x4 e;                                                        \
        e.x = aM[es].x; e.y = aM[es].y;                                 \
        e.z = aQ[es].x; e.w = aQ[es].y;                                 \
        (BUF)[i * RSTR + wmain] = e;                                    \
        if (whalo >= 0) (BUF)[i * RSTR + whalo] = e;                    \
        aM[es].x = 0.f; aM[es].y = 0.f;                                 \
        aQ[es].x = 0.f; aQ[es].y = 0.f;                                 \
    }

#define PREFETCH(CHUNK, PA, PB)                                         \
    _Pragma("unroll")                                                   \
    for (int i = 0; i < R; ++i) {                                       \
        int gr = row0 + RAD + (CHUNK) * R + i;                          \
        gr = (gr >= Hd) ? (2 * Hd - 2 - gr) : gr;                       \
        const long off = pbase + (long)gr * Wd + c;                     \
        (PA)[i] = img1[off];                                            \
        (PB)[i] = img2[off];                                            \
    }

__global__ __launch_bounds__(512, 4) void ssim_map_kernel(
    const float* __restrict__ img1,
    const float* __restrict__ img2,
    const float* __restrict__ kern,
    float* __restrict__ out)
{
    // packed {mS, mD, QS, QD} per column, R rows, transposed slots, x2 buffers
    __shared__ __align__(16) f32x4 hb[2][R * RSTR];   // 67 KB

    const int tid  = threadIdx.x;
    const int c    = tid;                       // owned column
    const int row0 = blockIdx.x * TH;
    const long pbase = (long)blockIdx.y * (long)(Hd * Wd);

    // ---- 1D gaussian (uniform -> SGPRs): g[j] = k[5][j]/sum ----
    float g[WS];
    {
        float s = 0.f;
#pragma unroll
        for (int j = 0; j < WS; ++j) s += kern[RAD * WS + j];
        const float inv = 1.0f / s;
#pragma unroll
        for (int j = 0; j < WS; ++j) g[j] = sgpr_f(kern[RAD * WS + j] * inv);
    }

    // ---- precomputed transposed write slots (loop-invariant) ----
    const int wmain = sw(c + RAD);              // staged element c+5
    int whalo = -1;
    if (c >= 1 && c <= RAD) whalo = sw(RAD - c);                       // left reflect
    else if (c >= Wd - 1 - RAD && c <= Wd - 2) whalo = sw(RAD + 1022 - c); // right

    // ---- ring accumulators, slot(out_row o) = o % 11 ----
    f32x2 aM[WS];   // {conv(S), conv(D)}
    f32x2 aQ[WS];   // {conv(S^2), conv(D^2)}
#pragma unroll
    for (int i = 0; i < WS; ++i) {
        aM[i].x = 0.f; aM[i].y = 0.f;
        aQ[i].x = 0.f; aQ[i].y = 0.f;
    }

    // ---- fill: input idx j=0..9 (rows row0-5+j), taps k<=j ----
#pragma unroll
    for (int j = 0; j < 2 * RAD; ++j) {
        int gr = row0 - RAD + j;                // uniform reflect -> SALU
        gr = (gr < 0) ? -gr : gr;
        gr = (gr >= Hd) ? (2 * Hd - 2 - gr) : gr;
        const long off = pbase + (long)gr * Wd + c;
        const float a = img1[off];
        const float b = img2[off];
        f32x2 sd; sd.x = a + b; sd.y = a - b;
        const f32x2 qq = sd * sd;               // v_pk_mul_f32
#pragma unroll
        for (int k = 0; k < WS; ++k) {
            if (k <= j) {
                const int slot = (j - k) % WS;  // static after unroll
                f32x2 w2; w2.x = g[k]; w2.y = g[k];
                aM[slot] = __builtin_elementwise_fma(w2, sd, aM[slot]);
                aQ[slot] = __builtin_elementwise_fma(w2, qq, aQ[slot]);
            }
        }
    }

    // ---- T14 prefetch registers, double set: V(k) consumes (k even ? A : B)
    float plaA[R], plbA[R], plaB[R], plbB[R];
    PREFETCH(0, plaA, plbA)                     // chunk 0
    PREFETCH(1, plaB, plbB)                     // chunk 1

    // ---- V(0) -> hb[0] (no barrier needed before first use) ----
    VPHASE(0, plaA, plbA, (&hb[0][0]))

    const int hr = tid >> 7;      // horizontal: row in chunk (0..3)
    const int hu = tid & 127;     // horizontal: out cols 4hu..4hu+3

#pragma unroll
    for (int ch = 0; ch < NCH; ++ch) {
        __syncthreads();          // hb[ch&1] complete; prior readers of
                                  // hb[(ch+1)&1] (H(ch-1)) are done

        // ---- issue chunk ch+2 loads into the set V(ch) already consumed ----
        if (ch + 2 < NCH) {
            if ((ch & 1) == 0) { PREFETCH(ch + 2, plaA, plbA) }
            else               { PREFETCH(ch + 2, plaB, plbB) }
        }

        // ---- H(ch): 4 cols x 1 row per thread, reads hb[ch&1] ----
        f32x2 hm[4], hq[4];
#pragma unroll
        for (int j = 0; j < 4; ++j) {
            hm[j].x = 0.f; hm[j].y = 0.f;
            hq[j].x = 0.f; hq[j].y = 0.f;
        }
        // base lane-stride = 1 element (16B): dense wave reads, offsets imm
        const f32x4* base = &hb[ch & 1][hr * RSTR + hu];
#pragma unroll
        for (int t = 0; t < 14; ++t) {          // staged elem 4hu+t (col 4hu+t-5)
            const f32x4 ft = base[(t & 3) * SPAN + (t >> 2)];   // ds_read_b128
            f32x2 fm; fm.x = ft.x; fm.y = ft.y;
            f32x2 fq; fq.x = ft.z; fq.y = ft.w;
#pragma unroll
            for (int j = 0; j < 4; ++j) {
                const int k = t - j;            // tap index, compile-time
                if (k >= 0 && k < WS) {
                    f32x2 w2; w2.x = g[k]; w2.y = g[k];
                    hm[j] = __builtin_elementwise_fma(w2, fm, hm[j]);
                    hq[j] = __builtin_elementwise_fma(w2, fq, hq[j]);
                }
            }
        }

        float rr[4];
#pragma unroll
        for (int j = 0; j < 4; ++j) {
            const f32x2 m = hm[j];              // {mS, mD}
            const f32x2 q = hq[j];              // {QS, QD}
            const f32x2 msq = m * m;            // {mS^2, mD^2}
            const float t1 = msq.x - msq.y;     // 4*mu1mu2
            const float t2 = msq.x + msq.y;     // 2*(mu1^2+mu2^2)
            const float q1 = q.x - q.y;         // 4*conv(ab)
            const float q2 = q.x + q.y;         // 2*conv(a^2+b^2)
            const float num = fmaf(0.5f, t1, C1c) * fmaf(0.5f, q1 - t1, C2c);
            const float den = fmaf(0.5f, t2, C1c) * fmaf(0.5f, q2 - t2, C2c);
            rr[j] = num * rcp_fast(den);
        }
        f32x4 res; res.x = rr[0]; res.y = rr[1]; res.z = rr[2]; res.w = rr[3];
        f32x4* po = (f32x4*)&out[pbase + (long)(row0 + ch * R + hr) * Wd + 4 * hu];
        *po = res;

        // ---- V(ch+1) -> hb[(ch+1)&1], overlaps H(ch) in this period ----
        if (ch + 1 < NCH) {
            if (((ch + 1) & 1) == 0) { VPHASE(ch + 1, plaA, plbA, (&hb[0][0])) }
            else                      { VPHASE(ch + 1, plaB, plbB, (&hb[1][0])) }
        }
    }
}

#undef VPHASE
#undef PREFETCH

} // namespace

extern "C" void kernel_launch(void* const* d_in, const int* in_sizes, int n_in,
                              void* d_out, int out_size, void* d_ws, size_t ws_size,
                              hipStream_t stream) {
    const float* img1 = (const float*)d_in[0];
    const float* img2 = (const float*)d_in[1];
    const float* kern = (const float*)d_in[2];
    float* outp = (float*)d_out;
    dim3 grid(Hd / TH, 48);   // 16 bands x 48 planes = 768 blocks
    ssim_map_kernel<<<grid, dim3(512), 0, stream>>>(img1, img2, kern, outp);
}